// Round 2
// baseline (3498.517 us; speedup 1.0000x reference)
//
#include <hip/hip_runtime.h>

#define TM 128
#define TN 128
#define TKK 16
#define CAP 38000
#define NEGV -1e10f
#define NMS_T 256
#define SLOTS 64            // register-resident capacity = NMS_T*SLOTS = 16384

// ---------------- Generic fp32 GEMM: C[z] = A[M,K(slice)] @ B[K,N] (+bias)(+relu) ----------
// Column remap: lane tx owns columns {tx*4+j | j<4} and {64+tx*4+j-4 | j>=4} so each
// B-fragment ds_read_b128 instruction touches 16 consecutive 16B chunks (bank-conflict-free).
__global__ __launch_bounds__(256) void gemm_f32(
    const float* __restrict__ A, const float* __restrict__ B,
    const float* __restrict__ bias, float* __restrict__ C,
    int M, int N, int K, int ksplit, int relu)
{
    __shared__ float As[TKK][TM + 4];
    __shared__ float Bs[TKK][TN + 4];
    const int tid = threadIdx.x;
    const int tx = tid & 15, ty = tid >> 4;
    const int m0 = blockIdx.y * TM, n0 = blockIdx.x * TN;
    const int z = blockIdx.z;
    const int kstart = z * ksplit;
    const int kend = (kstart + ksplit < K) ? (kstart + ksplit) : K;
    float* Cz = C + (size_t)z * (size_t)M * (size_t)N;
    const bool nvec = ((N & 3) == 0);

    float acc[8][8];
#pragma unroll
    for (int i = 0; i < 8; ++i)
#pragma unroll
        for (int j = 0; j < 8; ++j) acc[i][j] = 0.f;

    for (int kt = kstart; kt < kend; kt += TKK) {
        // stage A tile (transposed into LDS): 128 rows x 16 k
#pragma unroll
        for (int l = 0; l < 2; ++l) {
            int idx = tid + l * 256;          // 0..511
            int r = idx >> 2, kq = idx & 3;
            float4 v = make_float4(0.f, 0.f, 0.f, 0.f);
            int gr = m0 + r;
            if (gr < M)
                v = *reinterpret_cast<const float4*>(A + (size_t)gr * K + kt + (kq << 2));
            As[(kq << 2) + 0][r] = v.x;
            As[(kq << 2) + 1][r] = v.y;
            As[(kq << 2) + 2][r] = v.z;
            As[(kq << 2) + 3][r] = v.w;
        }
        // stage B tile: 16 k x 128 n
#pragma unroll
        for (int l = 0; l < 2; ++l) {
            int idx = tid + l * 256;
            int kk = idx >> 5, nq = idx & 31;
            int gn = n0 + (nq << 2);
            const float* bp = B + (size_t)(kt + kk) * N + gn;
            float4 v;
            if (nvec && gn + 3 < N) {
                v = *reinterpret_cast<const float4*>(bp);
            } else {
                v.x = (gn + 0 < N) ? bp[0] : 0.f;
                v.y = (gn + 1 < N) ? bp[1] : 0.f;
                v.z = (gn + 2 < N) ? bp[2] : 0.f;
                v.w = (gn + 3 < N) ? bp[3] : 0.f;
            }
            *reinterpret_cast<float4*>(&Bs[kk][nq << 2]) = v;
        }
        __syncthreads();
#pragma unroll
        for (int kk = 0; kk < TKK; ++kk) {
            float a[8], b[8];
            *reinterpret_cast<float4*>(&a[0]) = *reinterpret_cast<const float4*>(&As[kk][ty * 8]);
            *reinterpret_cast<float4*>(&a[4]) = *reinterpret_cast<const float4*>(&As[kk][ty * 8 + 4]);
            *reinterpret_cast<float4*>(&b[0]) = *reinterpret_cast<const float4*>(&Bs[kk][tx * 4]);
            *reinterpret_cast<float4*>(&b[4]) = *reinterpret_cast<const float4*>(&Bs[kk][64 + tx * 4]);
#pragma unroll
            for (int i = 0; i < 8; ++i)
#pragma unroll
                for (int j = 0; j < 8; ++j)
                    acc[i][j] = fmaf(a[i], b[j], acc[i][j]);
        }
        __syncthreads();
    }
#pragma unroll
    for (int i = 0; i < 8; ++i) {
        int gr = m0 + ty * 8 + i;
        if (gr >= M) continue;
#pragma unroll
        for (int j = 0; j < 8; ++j) {
            int gc = n0 + ((j < 4) ? (tx * 4 + j) : (64 + tx * 4 + (j - 4)));
            if (gc >= N) continue;
            float v = acc[i][j];
            if (bias) v += bias[gc];
            if (relu) v = fmaxf(v, 0.f);
            Cz[(size_t)gr * N + gc] = v;
        }
    }
}

// ---------------- combine split-K partials + bias (+relu), generic N ----------------
__global__ void combine_bias_act(const float* __restrict__ P, const float* __restrict__ bias,
                                 float* __restrict__ H, int total, int N, int nsplit,
                                 int pstride, int relu)
{
    int i = blockIdx.x * blockDim.x + threadIdx.x;
    if (i >= total) return;
    float s = P[i];
    for (int j = 1; j < nsplit; ++j) s += P[i + (size_t)j * (size_t)pstride];
    s += bias[i % N];
    if (relu) s = fmaxf(s, 0.f);
    H[i] = s;
}

// Python int scalars may arrive as int32 or float32 single-element arrays — sniff bits.
__device__ __forceinline__ float scalar_dim(const int* p)
{
    int iv = *p;
    return (iv > 0 && iv < (1 << 20)) ? (float)iv : *reinterpret_cast<const float*>(p);
}

// ---------------- decode + softmax + threshold + compact ----------------
__global__ __launch_bounds__(128) void decode_compact(
    const float* __restrict__ logits, const float* __restrict__ breg,
    const float4* __restrict__ proposals, const int* __restrict__ ihp,
    const int* __restrict__ iwp,
    float* __restrict__ cscore, float4* __restrict__ cboxn, float4* __restrict__ cboxo,
    int* __restrict__ cidx, int* __restrict__ cnt)
{
    const int n = blockIdx.x;
    const int c = threadIdx.x;
    __shared__ float sl[91];
    __shared__ float s_max, s_sum;
    if (c < 91) sl[c] = logits[n * 91 + c];
    __syncthreads();
    if (c == 0) {
        float m = sl[0];
        for (int i = 1; i < 91; ++i) m = fmaxf(m, sl[i]);
        float s = 0.f;
        for (int i = 0; i < 91; ++i) s += expf(sl[i] - m);
        s_max = m; s_sum = s;
    }
    __syncthreads();
    if (c < 1 || c >= 91) return;

    const float score = expf(sl[c] - s_max) / s_sum;
    const float Wim = scalar_dim(iwp), Him = scalar_dim(ihp);
    float4 p = proposals[n];
    float pw = p.z - p.x, ph = p.w - p.y;
    float pcx = p.x + 0.5f * pw, pcy = p.y + 0.5f * ph;
    const float* r4 = breg + (size_t)n * 364 + c * 4;
    float dxv = r4[0] / 10.f, dyv = r4[1] / 10.f;
    const float BCLIP = 4.135166556742356f;   // log(1000/16) rounded to f32
    float dwv = fminf(r4[2] / 5.f, BCLIP);
    float dhv = fminf(r4[3] / 5.f, BCLIP);
    float cx = dxv * pw + pcx, cy = dyv * ph + pcy;
    float w = expf(dwv) * pw, hh = expf(dhv) * ph;
    float x1 = cx - 0.5f * w, y1 = cy - 0.5f * hh;
    float x2 = cx + 0.5f * w, y2 = cy + 0.5f * hh;
    x1 = fminf(fmaxf(x1, 0.f), Wim);
    y1 = fminf(fmaxf(y1, 0.f), Him);
    x2 = fminf(fmaxf(x2, 0.f), Wim);
    y2 = fminf(fmaxf(y2, 0.f), Him);
    float bw = x2 - x1, bh = y2 - y1;
    if (score > 0.05f && bw >= 0.01f && bh >= 0.01f) {
        int pos = atomicAdd(cnt, 1);   // compiler wave-coalesces (m20)
        if (pos < CAP) {
            float off = (float)c * (fmaxf(Wim, Him) + 1.f);
            cscore[pos] = score;
            cboxn[pos] = make_float4(x1 + off, y1 + off, x2 + off, y2 + off);
            cboxo[pos] = make_float4(x1, y1, x2, y2);
            cidx[pos] = n * 90 + (c - 1);
        }
    }
}

// ---------------- greedy NMS: register-resident candidates, fused suppress+argmax ----------
__global__ __launch_bounds__(NMS_T, 1) void nms_kernel(
    float* __restrict__ sm, const float4* __restrict__ cboxn,
    const float4* __restrict__ cboxo, const int* __restrict__ cidx,
    const int* __restrict__ cnt, float* __restrict__ out)
{
    const int tid = threadIdx.x;
    int M = *cnt;
    if (M > CAP) M = CAP;

    // Load candidates into registers: slot j of thread t holds element t + j*NMS_T.
    float sc[SLOTS]; float4 bx[SLOTS]; int ci[SLOTS];
#pragma unroll
    for (int j = 0; j < SLOTS; ++j) {
        int i = tid + j * NMS_T;
        bool v = (i < M);
        sc[j] = v ? sm[i] : -3.0e38f;
        bx[j] = v ? cboxn[i] : make_float4(0.f, 0.f, 0.f, 0.f);
        ci[j] = v ? cidx[i] : 0x7fffffff;
    }

    __shared__ float red_s[4];
    __shared__ int   red_c[4];
    __shared__ float4 selb_sh;
    __shared__ int sel_ci_sh, sel_valid_sh;
    __shared__ float sel_sc_sh;

    float px1 = 0.f, py1 = 0.f, px2 = 0.f, py2 = 0.f, parea = 0.f;
    int pci = -1; bool pvalid = false;

    for (int k = 0; k < 100; ++k) {
        float best = -3.3e38f; int bc = 0x7fffffff;
        // fused: suppress-by-previous-selection, then argmax accumulate
#pragma unroll
        for (int j = 0; j < SLOTS; ++j) {
            if (pvalid) {
                float xx1 = fmaxf(px1, bx[j].x), yy1 = fmaxf(py1, bx[j].y);
                float xx2 = fminf(px2, bx[j].z), yy2 = fminf(py2, bx[j].w);
                float inter = fmaxf(xx2 - xx1, 0.f) * fmaxf(yy2 - yy1, 0.f);
                float area = (bx[j].z - bx[j].x) * (bx[j].w - bx[j].y);
                // iou > 0.5  <=>  3*inter > parea + area + eps   (denominator > 0)
                if (3.f * inter > parea + area + 1e-9f || ci[j] == pci) sc[j] = NEGV;
            }
            float v = sc[j];
            if (v > best || (v == best && ci[j] < bc)) { best = v; bc = ci[j]; }
        }
        // overflow region (M > 16384) — correctness fallback via global memory
        for (int i = NMS_T * SLOTS + tid; i < M; i += NMS_T) {
            float v = sm[i];
            if (pvalid && v > -5e9f) {
                float4 b = cboxn[i];
                float xx1 = fmaxf(px1, b.x), yy1 = fmaxf(py1, b.y);
                float xx2 = fminf(px2, b.z), yy2 = fminf(py2, b.w);
                float inter = fmaxf(xx2 - xx1, 0.f) * fmaxf(yy2 - yy1, 0.f);
                float area = (b.z - b.x) * (b.w - b.y);
                if (3.f * inter > parea + area + 1e-9f || cidx[i] == pci) { v = NEGV; sm[i] = NEGV; }
            }
            int cii = cidx[i];
            if (v > best || (v == best && cii < bc)) { best = v; bc = cii; }
        }
        // wave (64) reduction, tie-break on smaller flat index
#pragma unroll
        for (int d = 32; d >= 1; d >>= 1) {
            float ob = __shfl_down(best, d, 64);
            int obc = __shfl_down(bc, d, 64);
            if (ob > best || (ob == best && obc < bc)) { best = ob; bc = obc; }
        }
        if ((tid & 63) == 0) { red_s[tid >> 6] = best; red_c[tid >> 6] = bc; }
        __syncthreads();
        if (tid == 0) {
            float b2 = red_s[0]; int c2 = red_c[0];
            for (int w = 1; w < 4; ++w) {
                if (red_s[w] > b2 || (red_s[w] == b2 && red_c[w] < c2)) { b2 = red_s[w]; c2 = red_c[w]; }
            }
            bool valid = (b2 > NEGV * 0.5f);
            sel_valid_sh = valid ? 1 : 0;
            sel_ci_sh = c2;
            sel_sc_sh = b2;
            if (!valid) {
                out[k * 4 + 0] = 0.f; out[k * 4 + 1] = 0.f;
                out[k * 4 + 2] = 0.f; out[k * 4 + 3] = 0.f;
                out[400 + k] = 0.f; out[500 + k] = 0.f;
            }
        }
        __syncthreads();
        const int sv = sel_valid_sh;
        const int sci = sel_ci_sh;
        const float ssc = sel_sc_sh;
        if (sv) {
            // owner (unique cidx) broadcasts its box and writes this detection's outputs
#pragma unroll
            for (int j = 0; j < SLOTS; ++j) {
                if (ci[j] == sci) {
                    selb_sh = bx[j];
                    int i = tid + j * NMS_T;
                    float4 bo = cboxo[i];
                    out[k * 4 + 0] = bo.x; out[k * 4 + 1] = bo.y;
                    out[k * 4 + 2] = bo.z; out[k * 4 + 3] = bo.w;
                    out[400 + k] = ssc;
                    out[500 + k] = (float)((sci % 90) + 1);
                }
            }
            for (int i = NMS_T * SLOTS + tid; i < M; i += NMS_T) {
                if (cidx[i] == sci) {
                    selb_sh = cboxn[i];
                    float4 bo = cboxo[i];
                    out[k * 4 + 0] = bo.x; out[k * 4 + 1] = bo.y;
                    out[k * 4 + 2] = bo.z; out[k * 4 + 3] = bo.w;
                    out[400 + k] = ssc;
                    out[500 + k] = (float)((sci % 90) + 1);
                }
            }
        }
        __syncthreads();
        if (sv) {
            float4 s = selb_sh;
            px1 = s.x; py1 = s.y; px2 = s.z; py2 = s.w;
            parea = (s.z - s.x) * (s.w - s.y);
            pci = sci; pvalid = true;
        } else {
            pvalid = false;
        }
        __syncthreads();
    }
}

// ------------------------------------------------------------------------
extern "C" void kernel_launch(void* const* d_in, const int* in_sizes, int n_in,
                              void* d_out, int out_size, void* d_ws, size_t ws_size,
                              hipStream_t stream)
{
    const float* bf    = (const float*)d_in[0];
    const float* props = (const float*)d_in[1];
    const float* W1    = (const float*)d_in[2];
    const float* b1    = (const float*)d_in[3];
    const float* W2    = (const float*)d_in[4];
    const float* b2    = (const float*)d_in[5];
    const float* Wc    = (const float*)d_in[6];
    const float* bc    = (const float*)d_in[7];
    const float* Wr    = (const float*)d_in[8];
    const float* br    = (const float*)d_in[9];
    const int*   ihp   = (const int*)d_in[10];
    const int*   iwp   = (const int*)d_in[11];
    float* ws  = (float*)d_ws;
    float* out = (float*)d_out;

    const size_t MN = 2000ull * 1024ull;        // 2,048,000
    const size_t NLOG = 2000ull * 91ull;        // 182,000
    const size_t NREG = 2000ull * 364ull;       // 728,000
    const size_t TAILF = MN /*H1*/ + MN /*H2*/ + NLOG + NREG + (size_t)CAP * 10 + 8;
    const size_t ws_floats = ws_size / 4;

    // choose GEMM1 split; the partials region is reused by GEMM2/head partials later
    int z1 = 2;
    if (ws_floats >= TAILF + 8 * MN) z1 = 8;
    else if (ws_floats >= TAILF + 4 * MN) z1 = 4;
    const size_t REUSE = (size_t)z1 * MN;
    int z2 = (REUSE >= 4 * MN) ? 4 : z1;              // GEMM2 split
    int zh = (REUSE >= 8 * NREG) ? 8 : 4;             // head splits

    float* P    = ws;                    // REUSE floats (partials, phase-reused)
    float* H1   = P + REUSE;
    float* H2   = H1 + MN;
    float* LOG  = H2 + MN;
    float* BREG = LOG + NLOG;
    float* CS   = BREG + NREG;
    float* BN   = CS + CAP;
    float* BO   = BN + (size_t)CAP * 4;
    int*   CI   = (int*)(BO + (size_t)CAP * 4);
    int*   CNT  = CI + CAP;

    // 1) GEMM1 split-K partials: P[z] = bf @ W1[kslice]  (2000x12544x1024)
    gemm_f32<<<dim3(8, 16, z1), 256, 0, stream>>>(bf, W1, nullptr, P,
                                                  2000, 1024, 12544, 12544 / z1, 0);
    combine_bias_act<<<(int)((MN + 255) / 256), 256, 0, stream>>>(P, b1, H1,
                                                  (int)MN, 1024, z1, (int)MN, 1);
    // 2) H2 = relu(H1 @ W2 + b2)   (2000x1024x1024)
    gemm_f32<<<dim3(8, 16, z2), 256, 0, stream>>>(H1, W2, nullptr, P,
                                                  2000, 1024, 1024, 1024 / z2, 0);
    combine_bias_act<<<(int)((MN + 255) / 256), 256, 0, stream>>>(P, b2, H2,
                                                  (int)MN, 1024, z2, (int)MN, 1);
    // 3) heads: logits (2000x1024x91), box_reg (2000x1024x364)
    gemm_f32<<<dim3(1, 16, zh), 256, 0, stream>>>(H2, Wc, nullptr, P,
                                                  2000, 91, 1024, 1024 / zh, 0);
    combine_bias_act<<<(int)((NLOG + 255) / 256), 256, 0, stream>>>(P, bc, LOG,
                                                  (int)NLOG, 91, zh, (int)NLOG, 0);
    gemm_f32<<<dim3(3, 16, zh), 256, 0, stream>>>(H2, Wr, nullptr, P,
                                                  2000, 364, 1024, 1024 / zh, 0);
    combine_bias_act<<<(int)((NREG + 255) / 256), 256, 0, stream>>>(P, br, BREG,
                                                  (int)NREG, 364, zh, (int)NREG, 0);
    // 4) decode + softmax + threshold + compaction
    hipMemsetAsync(CNT, 0, sizeof(int), stream);
    decode_compact<<<2000, 128, 0, stream>>>(LOG, BREG, (const float4*)props, ihp, iwp,
                                             CS, (float4*)BN, (float4*)BO, CI, CNT);
    // 5) greedy NMS + output gather (boxes[400] | scores[100] | labels[100])
    nms_kernel<<<1, NMS_T, 0, stream>>>(CS, (const float4*)BN, (const float4*)BO, CI, CNT, out);
}

// Round 3
// 1294.719 us; speedup vs baseline: 2.7021x; 2.7021x over previous
//
#include <hip/hip_runtime.h>

#define TM 128
#define TN 128
#define TKK 16
#define CPC 2000          // max candidates per class (one per proposal)
#define SPC 100           // max survivors per class we ever need
#define NCLS 90

// ---------------- Generic fp32 GEMM: C[z] = A[M,K(slice)] @ B[K,N] ----------
__global__ __launch_bounds__(256) void gemm_f32(
    const float* __restrict__ A, const float* __restrict__ B,
    const float* __restrict__ bias, float* __restrict__ C,
    int M, int N, int K, int ksplit, int relu)
{
    __shared__ float As[TKK][TM + 4];
    __shared__ float Bs[TKK][TN + 4];
    const int tid = threadIdx.x;
    const int tx = tid & 15, ty = tid >> 4;
    const int m0 = blockIdx.y * TM, n0 = blockIdx.x * TN;
    const int z = blockIdx.z;
    const int kstart = z * ksplit;
    const int kend = (kstart + ksplit < K) ? (kstart + ksplit) : K;
    float* Cz = C + (size_t)z * (size_t)M * (size_t)N;
    const bool nvec = ((N & 3) == 0);

    float acc[8][8];
#pragma unroll
    for (int i = 0; i < 8; ++i)
#pragma unroll
        for (int j = 0; j < 8; ++j) acc[i][j] = 0.f;

    for (int kt = kstart; kt < kend; kt += TKK) {
#pragma unroll
        for (int l = 0; l < 2; ++l) {
            int idx = tid + l * 256;
            int r = idx >> 2, kq = idx & 3;
            float4 v = make_float4(0.f, 0.f, 0.f, 0.f);
            int gr = m0 + r;
            if (gr < M)
                v = *reinterpret_cast<const float4*>(A + (size_t)gr * K + kt + (kq << 2));
            As[(kq << 2) + 0][r] = v.x;
            As[(kq << 2) + 1][r] = v.y;
            As[(kq << 2) + 2][r] = v.z;
            As[(kq << 2) + 3][r] = v.w;
        }
#pragma unroll
        for (int l = 0; l < 2; ++l) {
            int idx = tid + l * 256;
            int kk = idx >> 5, nq = idx & 31;
            int gn = n0 + (nq << 2);
            const float* bp = B + (size_t)(kt + kk) * N + gn;
            float4 v;
            if (nvec && gn + 3 < N) {
                v = *reinterpret_cast<const float4*>(bp);
            } else {
                v.x = (gn + 0 < N) ? bp[0] : 0.f;
                v.y = (gn + 1 < N) ? bp[1] : 0.f;
                v.z = (gn + 2 < N) ? bp[2] : 0.f;
                v.w = (gn + 3 < N) ? bp[3] : 0.f;
            }
            *reinterpret_cast<float4*>(&Bs[kk][nq << 2]) = v;
        }
        __syncthreads();
#pragma unroll
        for (int kk = 0; kk < TKK; ++kk) {
            float a[8], b[8];
            *reinterpret_cast<float4*>(&a[0]) = *reinterpret_cast<const float4*>(&As[kk][ty * 8]);
            *reinterpret_cast<float4*>(&a[4]) = *reinterpret_cast<const float4*>(&As[kk][ty * 8 + 4]);
            *reinterpret_cast<float4*>(&b[0]) = *reinterpret_cast<const float4*>(&Bs[kk][tx * 4]);
            *reinterpret_cast<float4*>(&b[4]) = *reinterpret_cast<const float4*>(&Bs[kk][64 + tx * 4]);
#pragma unroll
            for (int i = 0; i < 8; ++i)
#pragma unroll
                for (int j = 0; j < 8; ++j)
                    acc[i][j] = fmaf(a[i], b[j], acc[i][j]);
        }
        __syncthreads();
    }
#pragma unroll
    for (int i = 0; i < 8; ++i) {
        int gr = m0 + ty * 8 + i;
        if (gr >= M) continue;
#pragma unroll
        for (int j = 0; j < 8; ++j) {
            int gc = n0 + ((j < 4) ? (tx * 4 + j) : (64 + tx * 4 + (j - 4)));
            if (gc >= N) continue;
            float v = acc[i][j];
            if (bias) v += bias[gc];
            if (relu) v = fmaxf(v, 0.f);
            Cz[(size_t)gr * N + gc] = v;
        }
    }
}

// ---------------- combine split-K partials + bias (+relu) ----------------
__global__ void combine_bias_act(const float* __restrict__ P, const float* __restrict__ bias,
                                 float* __restrict__ H, int total, int N, int nsplit,
                                 int pstride, int relu)
{
    int i = blockIdx.x * blockDim.x + threadIdx.x;
    if (i >= total) return;
    float s = P[i];
    for (int j = 1; j < nsplit; ++j) s += P[i + (size_t)j * (size_t)pstride];
    s += bias[i % N];
    if (relu) s = fmaxf(s, 0.f);
    H[i] = s;
}

// Python int scalars may arrive as int32 or float32 single-element arrays — sniff bits.
__device__ __forceinline__ float scalar_dim(const int* p)
{
    int iv = *p;
    return (iv > 0 && iv < (1 << 20)) ? (float)iv : *reinterpret_cast<const float*>(p);
}

// ---------------- decode + softmax + threshold + per-class bucket compact ----------------
__global__ __launch_bounds__(128) void decode_compact(
    const float* __restrict__ logits, const float* __restrict__ breg,
    const float4* __restrict__ proposals, const int* __restrict__ ihp,
    const int* __restrict__ iwp,
    float4* __restrict__ cbox, float* __restrict__ cscore, int* __restrict__ cn,
    int* __restrict__ ccnt)
{
    const int n = blockIdx.x;
    const int c = threadIdx.x;
    __shared__ float sl[91];
    __shared__ float s_max, s_sum;
    if (c < 91) sl[c] = logits[n * 91 + c];
    __syncthreads();
    if (c == 0) {
        float m = sl[0];
        for (int i = 1; i < 91; ++i) m = fmaxf(m, sl[i]);
        float s = 0.f;
        for (int i = 0; i < 91; ++i) s += expf(sl[i] - m);
        s_max = m; s_sum = s;
    }
    __syncthreads();
    if (c < 1 || c >= 91) return;

    const float score = expf(sl[c] - s_max) / s_sum;
    const float Wim = scalar_dim(iwp), Him = scalar_dim(ihp);
    float4 p = proposals[n];
    float pw = p.z - p.x, ph = p.w - p.y;
    float pcx = p.x + 0.5f * pw, pcy = p.y + 0.5f * ph;
    const float* r4 = breg + (size_t)n * 364 + c * 4;
    float dxv = r4[0] / 10.f, dyv = r4[1] / 10.f;
    const float BCLIP = 4.135166556742356f;   // log(1000/16) rounded to f32
    float dwv = fminf(r4[2] / 5.f, BCLIP);
    float dhv = fminf(r4[3] / 5.f, BCLIP);
    float cx = dxv * pw + pcx, cy = dyv * ph + pcy;
    float w = expf(dwv) * pw, hh = expf(dhv) * ph;
    float x1 = cx - 0.5f * w, y1 = cy - 0.5f * hh;
    float x2 = cx + 0.5f * w, y2 = cy + 0.5f * hh;
    x1 = fminf(fmaxf(x1, 0.f), Wim);
    y1 = fminf(fmaxf(y1, 0.f), Him);
    x2 = fminf(fmaxf(x2, 0.f), Wim);
    y2 = fminf(fmaxf(y2, 0.f), Him);
    float bw = x2 - x1, bh = y2 - y1;
    if (score > 0.05f && bw >= 0.01f && bh >= 0.01f) {
        int cls = c - 1;
        int pos = atomicAdd(&ccnt[cls], 1);
        if (pos < CPC) {
            cbox[cls * CPC + pos] = make_float4(x1, y1, x2, y2);
            cscore[cls * CPC + pos] = score;
            cn[cls * CPC + pos] = n;
        }
    }
}

// ---------------- per-class greedy NMS (one block per class, LDS-resident) ----------------
// key = (monotone-remapped score bits << 32) | ~(flat idx)  → u64 max == argmax w/ jnp tie-break
__global__ __launch_bounds__(256) void nms_class(
    const float4* __restrict__ cbox, const float* __restrict__ cscore,
    const int* __restrict__ cn, const int* __restrict__ ccnt,
    float4* __restrict__ sbox, float* __restrict__ sscore,
    unsigned long long* __restrict__ skey, int* __restrict__ scnt)
{
    const int cls = blockIdx.x;
    const int tid = threadIdx.x;
    int cnt = ccnt[cls]; if (cnt > CPC) cnt = CPC;

    __shared__ float4 cb[CPC];                    // 32 KB
    __shared__ unsigned long long keys[CPC];      // 16 KB
    __shared__ unsigned long long red[4];
    __shared__ float4 selsh;
    __shared__ int selidx_sh;

    for (int i = tid; i < cnt; i += 256) {
        cb[i] = cbox[cls * CPC + i];
        unsigned int sb = __float_as_uint(cscore[cls * CPC + i]);
        sb ^= (sb >> 31) ? 0xFFFFFFFFu : 0x80000000u;       // order-preserving remap
        unsigned int flat = (unsigned)cn[cls * CPC + i] * 90u + (unsigned)cls;
        keys[i] = ((unsigned long long)sb << 32) | (unsigned long long)(0xFFFFFFFFu - flat);
    }
    __syncthreads();

    int sel = 0;
    while (sel < SPC) {
        unsigned long long best = 0ull;
        for (int i = tid; i < cnt; i += 256) {
            unsigned long long k = keys[i];
            if (k > best) best = k;
        }
#pragma unroll
        for (int d = 32; d >= 1; d >>= 1) {
            unsigned long long o = __shfl_down(best, d, 64);
            if (o > best) best = o;
        }
        if ((tid & 63) == 0) red[tid >> 6] = best;
        __syncthreads();
        unsigned long long gbest = red[0];
        if (red[1] > gbest) gbest = red[1];
        if (red[2] > gbest) gbest = red[2];
        if (red[3] > gbest) gbest = red[3];
        if (gbest == 0ull) break;                 // class exhausted
        // unique owner (keys are distinct) publishes the selected box
        for (int i = tid; i < cnt; i += 256)
            if (keys[i] == gbest) { selsh = cb[i]; selidx_sh = i; }
        __syncthreads();
        float4 s = selsh;
        const int si = selidx_sh;
        const float sa = (s.z - s.x) * (s.w - s.y);
        if (tid == 0) {
            sbox[cls * SPC + sel] = s;
            unsigned int sb = (unsigned int)(gbest >> 32);
            sb ^= (sb >> 31) ? 0x80000000u : 0xFFFFFFFFu;   // inverse remap
            sscore[cls * SPC + sel] = __uint_as_float(sb);
            skey[cls * SPC + sel] = gbest;
        }
        for (int i = tid; i < cnt; i += 256) {
            float4 b = cb[i];
            float xx1 = fmaxf(s.x, b.x), yy1 = fmaxf(s.y, b.y);
            float xx2 = fminf(s.z, b.z), yy2 = fminf(s.w, b.w);
            float inter = fmaxf(xx2 - xx1, 0.f) * fmaxf(yy2 - yy1, 0.f);
            float area = (b.z - b.x) * (b.w - b.y);
            // iou > 0.5  <=>  3*inter > sa + area + 1e-9
            if (3.f * inter > sa + area + 1e-9f || i == si) keys[i] = 0ull;
        }
        ++sel;
        __syncthreads();
    }
    if (tid == 0) scnt[cls] = sel;
}

// ---------------- 90-way merge of per-class survivor chains (already score-sorted) --------
__global__ __launch_bounds__(128) void nms_merge(
    const float4* __restrict__ sbox, const float* __restrict__ sscore,
    const unsigned long long* __restrict__ skey, const int* __restrict__ scnt,
    float* __restrict__ out)
{
    const int tid = threadIdx.x;
    __shared__ int head[NCLS];
    __shared__ unsigned long long red[2];
    __shared__ int selc_sh;
    if (tid < NCLS) head[tid] = 0;
    __syncthreads();

    for (int k = 0; k < 100; ++k) {
        unsigned long long key = 0ull;
        if (tid < NCLS && head[tid] < scnt[tid]) key = skey[tid * SPC + head[tid]];
        unsigned long long mykey = key;
#pragma unroll
        for (int d = 32; d >= 1; d >>= 1) {
            unsigned long long o = __shfl_down(key, d, 64);
            if (o > key) key = o;
        }
        if ((tid & 63) == 0) red[tid >> 6] = key;
        if (tid == 0) selc_sh = -1;
        __syncthreads();
        unsigned long long gbest = red[0] > red[1] ? red[0] : red[1];
        if (gbest != 0ull && mykey == gbest) selc_sh = tid;   // unique (keys distinct)
        __syncthreads();
        const int c = selc_sh;
        if (tid == 0) {
            if (c >= 0) {
                int h = head[c];
                float4 b = sbox[c * SPC + h];
                out[k * 4 + 0] = b.x; out[k * 4 + 1] = b.y;
                out[k * 4 + 2] = b.z; out[k * 4 + 3] = b.w;
                out[400 + k] = sscore[c * SPC + h];
                out[500 + k] = (float)(c + 1);
            } else {
                out[k * 4 + 0] = 0.f; out[k * 4 + 1] = 0.f;
                out[k * 4 + 2] = 0.f; out[k * 4 + 3] = 0.f;
                out[400 + k] = 0.f; out[500 + k] = 0.f;
            }
        }
        if (c >= 0 && tid == c) head[c]++;
        __syncthreads();
    }
}

// ------------------------------------------------------------------------
extern "C" void kernel_launch(void* const* d_in, const int* in_sizes, int n_in,
                              void* d_out, int out_size, void* d_ws, size_t ws_size,
                              hipStream_t stream)
{
    const float* bf    = (const float*)d_in[0];
    const float* props = (const float*)d_in[1];
    const float* W1    = (const float*)d_in[2];
    const float* b1    = (const float*)d_in[3];
    const float* W2    = (const float*)d_in[4];
    const float* b2    = (const float*)d_in[5];
    const float* Wc    = (const float*)d_in[6];
    const float* bc    = (const float*)d_in[7];
    const float* Wr    = (const float*)d_in[8];
    const float* br    = (const float*)d_in[9];
    const int*   ihp   = (const int*)d_in[10];
    const int*   iwp   = (const int*)d_in[11];
    float* ws  = (float*)d_ws;
    float* out = (float*)d_out;

    const size_t MN   = 2000ull * 1024ull;      // 2,048,000
    const size_t NLOG = 2000ull * 91ull;        // 182,000
    const size_t NREG = 2000ull * 364ull;       // 728,000
    const size_t NMSF = (size_t)NCLS * CPC * 6  // cbox(4)+cscore+cn
                      + (size_t)NCLS * SPC * 7  // sbox(4)+sscore+skey(2)
                      + 256;                    // counters
    const size_t TAILF = 2 * MN + NLOG + NREG + NMSF;
    const size_t ws_floats = ws_size / 4;

    int z1 = 2;
    if (ws_floats >= TAILF + 8 * MN) z1 = 8;
    else if (ws_floats >= TAILF + 4 * MN) z1 = 4;
    const size_t REUSE = (size_t)z1 * MN;
    int z2 = (REUSE >= 4 * MN) ? 4 : z1;
    int zh = (REUSE >= 8 * NREG) ? 8 : 4;

    float* P      = ws;                         // partials, phase-reused
    float* H1     = P + REUSE;
    float* H2     = H1 + MN;
    float* LOG    = H2 + MN;
    float* BREG   = LOG + NLOG;
    float* CBOX   = BREG + NREG;                            // 90*2000*4
    float* CSCORE = CBOX + (size_t)NCLS * CPC * 4;          // 90*2000
    int*   CN     = (int*)(CSCORE + (size_t)NCLS * CPC);    // 90*2000
    float* SBOX   = (float*)(CN + (size_t)NCLS * CPC);      // 90*100*4
    float* SSCORE = SBOX + (size_t)NCLS * SPC * 4;          // 90*100
    unsigned long long* SKEY = (unsigned long long*)(SSCORE + (size_t)NCLS * SPC);
    int*   CCNT   = (int*)(SKEY + (size_t)NCLS * SPC);      // 90
    int*   SCNT   = CCNT + NCLS;                            // 90

    // 1) GEMM1: H1 = relu(bf @ W1 + b1)   (2000x12544x1024)
    gemm_f32<<<dim3(8, 16, z1), 256, 0, stream>>>(bf, W1, nullptr, P,
                                                  2000, 1024, 12544, 12544 / z1, 0);
    combine_bias_act<<<(int)((MN + 255) / 256), 256, 0, stream>>>(P, b1, H1,
                                                  (int)MN, 1024, z1, (int)MN, 1);
    // 2) H2 = relu(H1 @ W2 + b2)   (2000x1024x1024)
    gemm_f32<<<dim3(8, 16, z2), 256, 0, stream>>>(H1, W2, nullptr, P,
                                                  2000, 1024, 1024, 1024 / z2, 0);
    combine_bias_act<<<(int)((MN + 255) / 256), 256, 0, stream>>>(P, b2, H2,
                                                  (int)MN, 1024, z2, (int)MN, 1);
    // 3) heads
    gemm_f32<<<dim3(1, 16, zh), 256, 0, stream>>>(H2, Wc, nullptr, P,
                                                  2000, 91, 1024, 1024 / zh, 0);
    combine_bias_act<<<(int)((NLOG + 255) / 256), 256, 0, stream>>>(P, bc, LOG,
                                                  (int)NLOG, 91, zh, (int)NLOG, 0);
    gemm_f32<<<dim3(3, 16, zh), 256, 0, stream>>>(H2, Wr, nullptr, P,
                                                  2000, 364, 1024, 1024 / zh, 0);
    combine_bias_act<<<(int)((NREG + 255) / 256), 256, 0, stream>>>(P, br, BREG,
                                                  (int)NREG, 364, zh, (int)NREG, 0);
    // 4) decode + softmax + threshold + per-class compaction
    hipMemsetAsync(CCNT, 0, 2 * NCLS * sizeof(int), stream);
    decode_compact<<<2000, 128, 0, stream>>>(LOG, BREG, (const float4*)props, ihp, iwp,
                                             (float4*)CBOX, CSCORE, CN, CCNT);
    // 5) per-class greedy NMS (parallel over 90 classes)
    nms_class<<<NCLS, 256, 0, stream>>>((const float4*)CBOX, CSCORE, CN, CCNT,
                                        (float4*)SBOX, SSCORE, SKEY, SCNT);
    // 6) merge survivor chains → top-100 (boxes[400] | scores[100] | labels[100])
    nms_merge<<<1, 128, 0, stream>>>((const float4*)SBOX, SSCORE, SKEY, SCNT, out);
}

// Round 4
// 1005.566 us; speedup vs baseline: 3.4792x; 1.2876x over previous
//
#include <hip/hip_runtime.h>

#define TM 128
#define TN 128
#define TKK 16
#define CPC 2000          // max candidates per class
#define SPC 100           // max survivors per class
#define NCLS 90

typedef __attribute__((ext_vector_type(8))) short bf16x8;
typedef __attribute__((ext_vector_type(4))) float f32x4;

// ---------------- helpers ----------------
__device__ __forceinline__ unsigned short f2bf_rne(float f) {
    unsigned u = __float_as_uint(f);
    return (unsigned short)((u + 0x7FFFu + ((u >> 16) & 1u)) >> 16);
}
__device__ __forceinline__ unsigned short f2bf_trunc(float f) {
    return (unsigned short)(__float_as_uint(f) >> 16);
}
__device__ __forceinline__ float bfhi_f32(float f) {   // float with mantissa truncated to bf16
    return __uint_as_float(__float_as_uint(f) & 0xFFFF0000u);
}
__device__ __forceinline__ void async_load16(const void* g, void* l) {
    __builtin_amdgcn_global_load_lds((const __attribute__((address_space(1))) unsigned int*)g,
                                     (__attribute__((address_space(3))) unsigned int*)l, 16, 0, 0);
}

// ---------------- split + transpose: W[K][N] fp32 -> Thi/Tlo [N][K] bf16 ----------------
__global__ __launch_bounds__(256) void split_transpose(
    const float* __restrict__ W, unsigned short* __restrict__ Thi,
    unsigned short* __restrict__ Tlo, int K, int N)
{
    __shared__ float tile[32][33];
    const int kt = blockIdx.x * 32, nt = blockIdx.y * 32;
    const int tx = threadIdx.x & 31, ty = threadIdx.x >> 5;   // 32 x 8
#pragma unroll
    for (int j = 0; j < 4; ++j) {
        int k = kt + ty + j * 8, n = nt + tx;
        tile[ty + j * 8][tx] = (k < K && n < N) ? W[(size_t)k * N + n] : 0.f;
    }
    __syncthreads();
#pragma unroll
    for (int j = 0; j < 4; ++j) {
        int n = nt + ty + j * 8, k = kt + tx;
        if (n < N && k < K) {
            float f = tile[tx][ty + j * 8];
            unsigned short hi = f2bf_trunc(f);
            unsigned short lo = f2bf_rne(f - bfhi_f32(f));
            Thi[(size_t)n * K + k] = hi;
            Tlo[(size_t)n * K + k] = lo;
        }
    }
}

// ---------------- bf16x3 MFMA GEMM over virtual K' = 3K ----------------
// C = A_hi*B_hi + A_lo*B_hi + A_hi*B_lo ; A fp32 [M][K] split on the fly,
// B pre-split+transposed bf16 [N][K] (hi/lo). 128x128 tile, 16x16x32 MFMA.
__global__ __launch_bounds__(256) void gemm_bf16x3(
    const float* __restrict__ A, const unsigned short* __restrict__ Bhi,
    const unsigned short* __restrict__ Blo, float* __restrict__ C,
    int M, int N, int K, int kp_len)
{
    __shared__ unsigned short Al[4096];   // 512 chunks x 8 bf16 (chunk c=kq*128+m at Al[c*8])
    __shared__ unsigned short Bl[4096];
    const int tid = threadIdx.x;
    const int wv = tid >> 6, ln = tid & 63;
    const int q = ln >> 4, lm = ln & 15;
    const int m0 = blockIdx.y * 128, n0 = blockIdx.x * 128;
    const int z = blockIdx.z;
    const int kp0 = z * kp_len, kp1 = kp0 + kp_len;
    const int arow_t = (wv >> 1) * 64, bcol_t = (wv & 1) * 64;

    f32x4 acc[4][4];
#pragma unroll
    for (int i = 0; i < 4; ++i)
#pragma unroll
        for (int j = 0; j < 4; ++j) acc[i][j] = (f32x4)0.f;

    // A staging role: thread t handles row r=t>>1, k-half h=t&1 (16 fp32)
    const int r = tid >> 1, h = tid & 1;
    const bool arow_ok = (m0 + r) < M;
    const float* Arow = A + (size_t)(m0 + r) * K + h * 16;

    for (int kp = kp0; kp < kp1; kp += 32) {
        const int phase = (kp >= K) + (kp >= 2 * K);     // 0:hi*hi 1:lo*hi 2:hi*lo
        const int kk = kp - phase * K;
        const unsigned short* Bt = (phase == 2) ? Blo : Bhi;
        const bool wantlo = (phase == 1);

        // ---- B tile: 512 chunks via global_load_lds (16 B/lane, lane-linear dest)
#pragma unroll
        for (int i = 0; i < 2; ++i) {
            int c = i * 256 + wv * 64 + ln;
            int kq = c >> 7, n = c & 127;
            async_load16(Bt + (size_t)(n0 + n) * K + kk + kq * 8,
                         &Bl[(size_t)(i * 256 + wv * 64) * 8]);
        }
        // ---- A tile: fp32 load + split-to-bf16 + ds_write
        float f[16];
        if (arow_ok) {
            const float4* ap = reinterpret_cast<const float4*>(Arow + kk);
#pragma unroll
            for (int e = 0; e < 4; ++e) {
                float4 v = ap[e];
                f[e * 4 + 0] = v.x; f[e * 4 + 1] = v.y; f[e * 4 + 2] = v.z; f[e * 4 + 3] = v.w;
            }
        } else {
#pragma unroll
            for (int e = 0; e < 16; ++e) f[e] = 0.f;
        }
        bf16x8 p0, p1;
        if (wantlo) {
#pragma unroll
            for (int e = 0; e < 8; ++e) p0[e] = (short)f2bf_rne(f[e] - bfhi_f32(f[e]));
#pragma unroll
            for (int e = 0; e < 8; ++e) p1[e] = (short)f2bf_rne(f[e + 8] - bfhi_f32(f[e + 8]));
        } else {
#pragma unroll
            for (int e = 0; e < 8; ++e) p0[e] = (short)f2bf_trunc(f[e]);
#pragma unroll
            for (int e = 0; e < 8; ++e) p1[e] = (short)f2bf_trunc(f[e + 8]);
        }
        *(bf16x8*)&Al[(size_t)((h * 2 + 0) * 128 + r) * 8] = p0;
        *(bf16x8*)&Al[(size_t)((h * 2 + 1) * 128 + r) * 8] = p1;
        __syncthreads();

        // ---- fragments + 16 MFMA
        bf16x8 af[4], bfr[4];
#pragma unroll
        for (int mi = 0; mi < 4; ++mi)
            af[mi] = *(const bf16x8*)&Al[(size_t)(q * 128 + arow_t + mi * 16 + lm) * 8];
#pragma unroll
        for (int ni = 0; ni < 4; ++ni)
            bfr[ni] = *(const bf16x8*)&Bl[(size_t)(q * 128 + bcol_t + ni * 16 + lm) * 8];
#pragma unroll
        for (int mi = 0; mi < 4; ++mi)
#pragma unroll
            for (int ni = 0; ni < 4; ++ni)
                acc[mi][ni] = __builtin_amdgcn_mfma_f32_16x16x32_bf16(af[mi], bfr[ni],
                                                                      acc[mi][ni], 0, 0, 0);
        __syncthreads();
    }

    // ---- store partials: C/D layout row=q*4+ri, col=lm
    float* Cz = C + (size_t)z * (size_t)M * (size_t)N;
#pragma unroll
    for (int mi = 0; mi < 4; ++mi)
#pragma unroll
        for (int ni = 0; ni < 4; ++ni)
#pragma unroll
            for (int ri = 0; ri < 4; ++ri) {
                int rr = m0 + arow_t + mi * 16 + q * 4 + ri;
                int cc = n0 + bcol_t + ni * 16 + lm;
                if (rr < M) Cz[(size_t)rr * N + cc] = acc[mi][ni][ri];
            }
}

// ---------------- fp32 vector GEMM (heads / fallback) ----------------
__global__ __launch_bounds__(256) void gemm_f32(
    const float* __restrict__ A, const float* __restrict__ B,
    const float* __restrict__ bias, float* __restrict__ C,
    int M, int N, int K, int ksplit, int relu)
{
    __shared__ float As[TKK][TM + 4];
    __shared__ float Bs[TKK][TN + 4];
    const int tid = threadIdx.x;
    const int tx = tid & 15, ty = tid >> 4;
    const int m0 = blockIdx.y * TM, n0 = blockIdx.x * TN;
    const int z = blockIdx.z;
    const int kstart = z * ksplit;
    const int kend = (kstart + ksplit < K) ? (kstart + ksplit) : K;
    float* Cz = C + (size_t)z * (size_t)M * (size_t)N;
    const bool nvec = ((N & 3) == 0);

    float acc[8][8];
#pragma unroll
    for (int i = 0; i < 8; ++i)
#pragma unroll
        for (int j = 0; j < 8; ++j) acc[i][j] = 0.f;

    for (int kt = kstart; kt < kend; kt += TKK) {
#pragma unroll
        for (int l = 0; l < 2; ++l) {
            int idx = tid + l * 256;
            int rr = idx >> 2, kq = idx & 3;
            float4 v = make_float4(0.f, 0.f, 0.f, 0.f);
            int gr = m0 + rr;
            if (gr < M)
                v = *reinterpret_cast<const float4*>(A + (size_t)gr * K + kt + (kq << 2));
            As[(kq << 2) + 0][rr] = v.x;
            As[(kq << 2) + 1][rr] = v.y;
            As[(kq << 2) + 2][rr] = v.z;
            As[(kq << 2) + 3][rr] = v.w;
        }
#pragma unroll
        for (int l = 0; l < 2; ++l) {
            int idx = tid + l * 256;
            int kk = idx >> 5, nq = idx & 31;
            int gn = n0 + (nq << 2);
            const float* bp = B + (size_t)(kt + kk) * N + gn;
            float4 v;
            if (nvec && gn + 3 < N) {
                v = *reinterpret_cast<const float4*>(bp);
            } else {
                v.x = (gn + 0 < N) ? bp[0] : 0.f;
                v.y = (gn + 1 < N) ? bp[1] : 0.f;
                v.z = (gn + 2 < N) ? bp[2] : 0.f;
                v.w = (gn + 3 < N) ? bp[3] : 0.f;
            }
            *reinterpret_cast<float4*>(&Bs[kk][nq << 2]) = v;
        }
        __syncthreads();
#pragma unroll
        for (int kk = 0; kk < TKK; ++kk) {
            float a[8], b[8];
            *reinterpret_cast<float4*>(&a[0]) = *reinterpret_cast<const float4*>(&As[kk][ty * 8]);
            *reinterpret_cast<float4*>(&a[4]) = *reinterpret_cast<const float4*>(&As[kk][ty * 8 + 4]);
            *reinterpret_cast<float4*>(&b[0]) = *reinterpret_cast<const float4*>(&Bs[kk][tx * 4]);
            *reinterpret_cast<float4*>(&b[4]) = *reinterpret_cast<const float4*>(&Bs[kk][64 + tx * 4]);
#pragma unroll
            for (int i = 0; i < 8; ++i)
#pragma unroll
                for (int j = 0; j < 8; ++j)
                    acc[i][j] = fmaf(a[i], b[j], acc[i][j]);
        }
        __syncthreads();
    }
#pragma unroll
    for (int i = 0; i < 8; ++i) {
        int gr = m0 + ty * 8 + i;
        if (gr >= M) continue;
#pragma unroll
        for (int j = 0; j < 8; ++j) {
            int gc = n0 + ((j < 4) ? (tx * 4 + j) : (64 + tx * 4 + (j - 4)));
            if (gc >= N) continue;
            float v = acc[i][j];
            if (bias) v += bias[gc];
            if (relu) v = fmaxf(v, 0.f);
            Cz[(size_t)gr * N + gc] = v;
        }
    }
}

// ---------------- combine split-K partials + bias (+relu) ----------------
__global__ void combine_bias_act(const float* __restrict__ P, const float* __restrict__ bias,
                                 float* __restrict__ H, int total, int N, int nsplit,
                                 int pstride, int relu)
{
    int i = blockIdx.x * blockDim.x + threadIdx.x;
    if (i >= total) return;
    float s = P[i];
    for (int j = 1; j < nsplit; ++j) s += P[i + (size_t)j * (size_t)pstride];
    s += bias[i % N];
    if (relu) s = fmaxf(s, 0.f);
    H[i] = s;
}

__device__ __forceinline__ float scalar_dim(const int* p)
{
    int iv = *p;
    return (iv > 0 && iv < (1 << 20)) ? (float)iv : *reinterpret_cast<const float*>(p);
}

// ---------------- decode + softmax + threshold + per-class bucket compact ----------------
__global__ __launch_bounds__(128) void decode_compact(
    const float* __restrict__ logits, const float* __restrict__ breg,
    const float4* __restrict__ proposals, const int* __restrict__ ihp,
    const int* __restrict__ iwp,
    float4* __restrict__ cbox, float* __restrict__ cscore, int* __restrict__ cn,
    int* __restrict__ ccnt)
{
    const int n = blockIdx.x;
    const int c = threadIdx.x;
    __shared__ float sl[91];
    __shared__ float s_max, s_sum;
    if (c < 91) sl[c] = logits[n * 91 + c];
    __syncthreads();
    if (c == 0) {
        float m = sl[0];
        for (int i = 1; i < 91; ++i) m = fmaxf(m, sl[i]);
        float s = 0.f;
        for (int i = 0; i < 91; ++i) s += expf(sl[i] - m);
        s_max = m; s_sum = s;
    }
    __syncthreads();
    if (c < 1 || c >= 91) return;

    const float score = expf(sl[c] - s_max) / s_sum;
    const float Wim = scalar_dim(iwp), Him = scalar_dim(ihp);
    float4 p = proposals[n];
    float pw = p.z - p.x, ph = p.w - p.y;
    float pcx = p.x + 0.5f * pw, pcy = p.y + 0.5f * ph;
    const float* r4 = breg + (size_t)n * 364 + c * 4;
    float dxv = r4[0] / 10.f, dyv = r4[1] / 10.f;
    const float BCLIP = 4.135166556742356f;
    float dwv = fminf(r4[2] / 5.f, BCLIP);
    float dhv = fminf(r4[3] / 5.f, BCLIP);
    float cx = dxv * pw + pcx, cy = dyv * ph + pcy;
    float w = expf(dwv) * pw, hh = expf(dhv) * ph;
    float x1 = cx - 0.5f * w, y1 = cy - 0.5f * hh;
    float x2 = cx + 0.5f * w, y2 = cy + 0.5f * hh;
    x1 = fminf(fmaxf(x1, 0.f), Wim);
    y1 = fminf(fmaxf(y1, 0.f), Him);
    x2 = fminf(fmaxf(x2, 0.f), Wim);
    y2 = fminf(fmaxf(y2, 0.f), Him);
    float bw = x2 - x1, bh = y2 - y1;
    if (score > 0.05f && bw >= 0.01f && bh >= 0.01f) {
        int cls = c - 1;
        int pos = atomicAdd(&ccnt[cls], 1);
        if (pos < CPC) {
            cbox[cls * CPC + pos] = make_float4(x1, y1, x2, y2);
            cscore[cls * CPC + pos] = score;
            cn[cls * CPC + pos] = n;
        }
    }
}

// ---------------- per-class greedy NMS ----------------
__global__ __launch_bounds__(256) void nms_class(
    const float4* __restrict__ cbox, const float* __restrict__ cscore,
    const int* __restrict__ cn, const int* __restrict__ ccnt,
    float4* __restrict__ sbox, float* __restrict__ sscore,
    unsigned long long* __restrict__ skey, int* __restrict__ scnt)
{
    const int cls = blockIdx.x;
    const int tid = threadIdx.x;
    int cnt = ccnt[cls]; if (cnt > CPC) cnt = CPC;

    __shared__ float4 cb[CPC];
    __shared__ unsigned long long keys[CPC];
    __shared__ unsigned long long red[4];
    __shared__ float4 selsh;
    __shared__ int selidx_sh;

    for (int i = tid; i < cnt; i += 256) {
        cb[i] = cbox[cls * CPC + i];
        unsigned int sb = __float_as_uint(cscore[cls * CPC + i]);
        sb ^= (sb >> 31) ? 0xFFFFFFFFu : 0x80000000u;
        unsigned int flat = (unsigned)cn[cls * CPC + i] * 90u + (unsigned)cls;
        keys[i] = ((unsigned long long)sb << 32) | (unsigned long long)(0xFFFFFFFFu - flat);
    }
    __syncthreads();

    int sel = 0;
    while (sel < SPC) {
        unsigned long long best = 0ull;
        for (int i = tid; i < cnt; i += 256) {
            unsigned long long k = keys[i];
            if (k > best) best = k;
        }
#pragma unroll
        for (int d = 32; d >= 1; d >>= 1) {
            unsigned long long o = __shfl_down(best, d, 64);
            if (o > best) best = o;
        }
        if ((tid & 63) == 0) red[tid >> 6] = best;
        __syncthreads();
        unsigned long long gbest = red[0];
        if (red[1] > gbest) gbest = red[1];
        if (red[2] > gbest) gbest = red[2];
        if (red[3] > gbest) gbest = red[3];
        if (gbest == 0ull) break;
        for (int i = tid; i < cnt; i += 256)
            if (keys[i] == gbest) { selsh = cb[i]; selidx_sh = i; }
        __syncthreads();
        float4 s = selsh;
        const int si = selidx_sh;
        const float sa = (s.z - s.x) * (s.w - s.y);
        if (tid == 0) {
            sbox[cls * SPC + sel] = s;
            unsigned int sb = (unsigned int)(gbest >> 32);
            sb ^= (sb >> 31) ? 0x80000000u : 0xFFFFFFFFu;
            sscore[cls * SPC + sel] = __uint_as_float(sb);
            skey[cls * SPC + sel] = gbest;
        }
        for (int i = tid; i < cnt; i += 256) {
            float4 b = cb[i];
            float xx1 = fmaxf(s.x, b.x), yy1 = fmaxf(s.y, b.y);
            float xx2 = fminf(s.z, b.z), yy2 = fminf(s.w, b.w);
            float inter = fmaxf(xx2 - xx1, 0.f) * fmaxf(yy2 - yy1, 0.f);
            float area = (b.z - b.x) * (b.w - b.y);
            if (3.f * inter > sa + area + 1e-9f || i == si) keys[i] = 0ull;
        }
        ++sel;
        __syncthreads();
    }
    if (tid == 0) scnt[cls] = sel;
}

// ---------------- 90-way merge ----------------
__global__ __launch_bounds__(128) void nms_merge(
    const float4* __restrict__ sbox, const float* __restrict__ sscore,
    const unsigned long long* __restrict__ skey, const int* __restrict__ scnt,
    float* __restrict__ out)
{
    const int tid = threadIdx.x;
    __shared__ int head[NCLS];
    __shared__ unsigned long long red[2];
    __shared__ int selc_sh;
    if (tid < NCLS) head[tid] = 0;
    __syncthreads();

    for (int k = 0; k < 100; ++k) {
        unsigned long long key = 0ull;
        if (tid < NCLS && head[tid] < scnt[tid]) key = skey[tid * SPC + head[tid]];
        unsigned long long mykey = key;
#pragma unroll
        for (int d = 32; d >= 1; d >>= 1) {
            unsigned long long o = __shfl_down(key, d, 64);
            if (o > key) key = o;
        }
        if ((tid & 63) == 0) red[tid >> 6] = key;
        if (tid == 0) selc_sh = -1;
        __syncthreads();
        unsigned long long gbest = red[0] > red[1] ? red[0] : red[1];
        if (gbest != 0ull && mykey == gbest) selc_sh = tid;
        __syncthreads();
        const int c = selc_sh;
        if (tid == 0) {
            if (c >= 0) {
                int h = head[c];
                float4 b = sbox[c * SPC + h];
                out[k * 4 + 0] = b.x; out[k * 4 + 1] = b.y;
                out[k * 4 + 2] = b.z; out[k * 4 + 3] = b.w;
                out[400 + k] = sscore[c * SPC + h];
                out[500 + k] = (float)(c + 1);
            } else {
                out[k * 4 + 0] = 0.f; out[k * 4 + 1] = 0.f;
                out[k * 4 + 2] = 0.f; out[k * 4 + 3] = 0.f;
                out[400 + k] = 0.f; out[500 + k] = 0.f;
            }
        }
        if (c >= 0 && tid == c) head[c]++;
        __syncthreads();
    }
}

// ------------------------------------------------------------------------
extern "C" void kernel_launch(void* const* d_in, const int* in_sizes, int n_in,
                              void* d_out, int out_size, void* d_ws, size_t ws_size,
                              hipStream_t stream)
{
    const float* bf    = (const float*)d_in[0];
    const float* props = (const float*)d_in[1];
    const float* W1    = (const float*)d_in[2];
    const float* b1    = (const float*)d_in[3];
    const float* W2    = (const float*)d_in[4];
    const float* b2    = (const float*)d_in[5];
    const float* Wc    = (const float*)d_in[6];
    const float* bc    = (const float*)d_in[7];
    const float* Wr    = (const float*)d_in[8];
    const float* br    = (const float*)d_in[9];
    const int*   ihp   = (const int*)d_in[10];
    const int*   iwp   = (const int*)d_in[11];
    float* ws  = (float*)d_ws;
    float* out = (float*)d_out;

    const size_t MN   = 2000ull * 1024ull;      // 2,048,000
    const size_t NLOG = 2000ull * 91ull;
    const size_t NREG = 2000ull * 364ull;
    const size_t ws_floats = ws_size / 4;

    // ---- MFMA-path layout (float units) ----
    const size_t BT1F = 1024ull * 12544ull / 2;   // one bf16 [N][K] array = 6,422,528 floats
    const size_t WT2F = 1024ull * 1024ull / 2;    // 524,288
    const size_t H1F  = 2048ull * 1024ull;
    const size_t NMSF = (size_t)NCLS * CPC * 6 + (size_t)NCLS * SPC * 7 + 256;
    const size_t FIXED = 2 * BT1F + 2 * WT2F + H1F + MN + NLOG + NREG + NMSF;

    int zm = 0;
    if (ws_floats >= FIXED + 6 * MN) zm = 6;
    else if (ws_floats >= FIXED + 4 * MN) zm = 4;
    else if (ws_floats >= FIXED + 2 * MN) zm = 2;

    if (zm > 0) {
        // ================= MFMA bf16x3 path =================
        unsigned short* BT1hi = (unsigned short*)ws;
        unsigned short* BT1lo = (unsigned short*)(ws + BT1F);
        unsigned short* WT2hi = (unsigned short*)(ws + 2 * BT1F);
        unsigned short* WT2lo = (unsigned short*)(ws + 2 * BT1F + WT2F);
        float* H1   = ws + 2 * BT1F + 2 * WT2F;
        float* H2   = H1 + H1F;
        float* LOG  = H2 + MN;
        float* BREG = LOG + NLOG;
        float* CBOX   = BREG + NREG;
        float* CSCORE = CBOX + (size_t)NCLS * CPC * 4;
        int*   CN     = (int*)(CSCORE + (size_t)NCLS * CPC);
        float* SBOX   = (float*)(CN + (size_t)NCLS * CPC);
        float* SSCORE = SBOX + (size_t)NCLS * SPC * 4;
        unsigned long long* SKEY = (unsigned long long*)(SSCORE + (size_t)NCLS * SPC);
        int*   CCNT = (int*)(SKEY + (size_t)NCLS * SPC);
        int*   SCNT = CCNT + NCLS;
        float* P = (float*)(SCNT + NCLS + 62);   // partials, zm*MN

        // 0) weight split+transpose
        split_transpose<<<dim3(392, 32), 256, 0, stream>>>(W1, BT1hi, BT1lo, 12544, 1024);
        split_transpose<<<dim3(32, 32), 256, 0, stream>>>(W2, WT2hi, WT2lo, 1024, 1024);
        // 1) GEMM1 bf16x3: virtual K'=3*12544
        gemm_bf16x3<<<dim3(8, 16, zm), 256, 0, stream>>>(bf, BT1hi, BT1lo, P,
                                                         2000, 1024, 12544, 37632 / zm);
        combine_bias_act<<<(int)((MN + 255) / 256), 256, 0, stream>>>(P, b1, H1,
                                                         (int)MN, 1024, zm, (int)MN, 1);
        // 2) GEMM2 bf16x3: K'=3072
        gemm_bf16x3<<<dim3(8, 16, zm), 256, 0, stream>>>(H1, WT2hi, WT2lo, P,
                                                         2000, 1024, 1024, 3072 / zm);
        combine_bias_act<<<(int)((MN + 255) / 256), 256, 0, stream>>>(P, b2, H2,
                                                         (int)MN, 1024, zm, (int)MN, 1);
        // 3) heads (fp32 vector path)
        int zh = (zm >= 4) ? 8 : 4;
        gemm_f32<<<dim3(1, 16, zh), 256, 0, stream>>>(H2, Wc, nullptr, P,
                                                      2000, 91, 1024, 1024 / zh, 0);
        combine_bias_act<<<(int)((NLOG + 255) / 256), 256, 0, stream>>>(P, bc, LOG,
                                                      (int)NLOG, 91, zh, (int)NLOG, 0);
        gemm_f32<<<dim3(3, 16, zh), 256, 0, stream>>>(H2, Wr, nullptr, P,
                                                      2000, 364, 1024, 1024 / zh, 0);
        combine_bias_act<<<(int)((NREG + 255) / 256), 256, 0, stream>>>(P, br, BREG,
                                                      (int)NREG, 364, zh, (int)NREG, 0);
        // 4) decode + compaction, 5) per-class NMS, 6) merge
        hipMemsetAsync(CCNT, 0, 2 * NCLS * sizeof(int), stream);
        decode_compact<<<2000, 128, 0, stream>>>(LOG, BREG, (const float4*)props, ihp, iwp,
                                                 (float4*)CBOX, CSCORE, CN, CCNT);
        nms_class<<<NCLS, 256, 0, stream>>>((const float4*)CBOX, CSCORE, CN, CCNT,
                                            (float4*)SBOX, SSCORE, SKEY, SCNT);
        nms_merge<<<1, 128, 0, stream>>>((const float4*)SBOX, SSCORE, SKEY, SCNT, out);
        return;
    }

    // ================= fallback: round-3 fp32 path =================
    const size_t NMSF2 = (size_t)NCLS * CPC * 6 + (size_t)NCLS * SPC * 7 + 256;
    const size_t TAILF = 2 * MN + NLOG + NREG + NMSF2;
    int z1 = 2;
    if (ws_floats >= TAILF + 8 * MN) z1 = 8;
    else if (ws_floats >= TAILF + 4 * MN) z1 = 4;
    const size_t REUSE = (size_t)z1 * MN;
    int zh = (REUSE >= 8 * NREG) ? 8 : 4;

    float* P      = ws;
    float* H1     = P + REUSE;
    float* H2     = H1 + MN;
    float* LOG    = H2 + MN;
    float* BREG   = LOG + NLOG;
    float* CBOX   = BREG + NREG;
    float* CSCORE = CBOX + (size_t)NCLS * CPC * 4;
    int*   CN     = (int*)(CSCORE + (size_t)NCLS * CPC);
    float* SBOX   = (float*)(CN + (size_t)NCLS * CPC);
    float* SSCORE = SBOX + (size_t)NCLS * SPC * 4;
    unsigned long long* SKEY = (unsigned long long*)(SSCORE + (size_t)NCLS * SPC);
    int*   CCNT   = (int*)(SKEY + (size_t)NCLS * SPC);
    int*   SCNT   = CCNT + NCLS;

    gemm_f32<<<dim3(8, 16, z1), 256, 0, stream>>>(bf, W1, nullptr, P,
                                                  2000, 1024, 12544, 12544 / z1, 0);
    combine_bias_act<<<(int)((MN + 255) / 256), 256, 0, stream>>>(P, b1, H1,
                                                  (int)MN, 1024, z1, (int)MN, 1);
    gemm_f32<<<dim3(8, 16, 4), 256, 0, stream>>>(H1, W2, nullptr, P,
                                                 2000, 1024, 1024, 256, 0);
    combine_bias_act<<<(int)((MN + 255) / 256), 256, 0, stream>>>(P, b2, H2,
                                                 (int)MN, 1024, 4, (int)MN, 1);
    gemm_f32<<<dim3(1, 16, zh), 256, 0, stream>>>(H2, Wc, nullptr, P,
                                                  2000, 91, 1024, 1024 / zh, 0);
    combine_bias_act<<<(int)((NLOG + 255) / 256), 256, 0, stream>>>(P, bc, LOG,
                                                  (int)NLOG, 91, zh, (int)NLOG, 0);
    gemm_f32<<<dim3(3, 16, zh), 256, 0, stream>>>(H2, Wr, nullptr, P,
                                                  2000, 364, 1024, 1024 / zh, 0);
    combine_bias_act<<<(int)((NREG + 255) / 256), 256, 0, stream>>>(P, br, BREG,
                                                  (int)NREG, 364, zh, (int)NREG, 0);
    hipMemsetAsync(CCNT, 0, 2 * NCLS * sizeof(int), stream);
    decode_compact<<<2000, 128, 0, stream>>>(LOG, BREG, (const float4*)props, ihp, iwp,
                                             (float4*)CBOX, CSCORE, CN, CCNT);
    nms_class<<<NCLS, 256, 0, stream>>>((const float4*)CBOX, CSCORE, CN, CCNT,
                                        (float4*)SBOX, SSCORE, SKEY, SCNT);
    nms_merge<<<1, 128, 0, stream>>>((const float4*)SBOX, SSCORE, SKEY, SCNT, out);
}

// Round 5
// 757.886 us; speedup vs baseline: 4.6162x; 1.3268x over previous
//
#include <hip/hip_runtime.h>

#define TM 128
#define TN 128
#define TKK 16
#define CPC 2000          // max candidates per class
#define SPC 100           // max survivors per class
#define NCLS 90

typedef __attribute__((ext_vector_type(8))) short bf16x8;
typedef __attribute__((ext_vector_type(4))) float f32x4;

// ---------------- helpers ----------------
__device__ __forceinline__ unsigned short f2bf_rne(float f) {
    unsigned u = __float_as_uint(f);
    return (unsigned short)((u + 0x7FFFu + ((u >> 16) & 1u)) >> 16);
}
__device__ __forceinline__ unsigned short f2bf_trunc(float f) {
    return (unsigned short)(__float_as_uint(f) >> 16);
}
__device__ __forceinline__ float bfhi_f32(float f) {
    return __uint_as_float(__float_as_uint(f) & 0xFFFF0000u);
}
__device__ __forceinline__ void async_load16(const void* g, void* l) {
    __builtin_amdgcn_global_load_lds((const __attribute__((address_space(1))) unsigned int*)g,
                                     (__attribute__((address_space(3))) unsigned int*)l, 16, 0, 0);
}

// ---------------- split + transpose: W[K][N] fp32 -> Thi/Tlo [N][K] bf16 ----------------
__global__ __launch_bounds__(256) void split_transpose(
    const float* __restrict__ W, unsigned short* __restrict__ Thi,
    unsigned short* __restrict__ Tlo, int K, int N)
{
    __shared__ float tile[32][33];
    const int kt = blockIdx.x * 32, nt = blockIdx.y * 32;
    const int tx = threadIdx.x & 31, ty = threadIdx.x >> 5;
#pragma unroll
    for (int j = 0; j < 4; ++j) {
        int k = kt + ty + j * 8, n = nt + tx;
        tile[ty + j * 8][tx] = (k < K && n < N) ? W[(size_t)k * N + n] : 0.f;
    }
    __syncthreads();
#pragma unroll
    for (int j = 0; j < 4; ++j) {
        int n = nt + ty + j * 8, k = kt + tx;
        if (n < N && k < K) {
            float f = tile[tx][ty + j * 8];
            Thi[(size_t)n * K + k] = f2bf_trunc(f);
            Tlo[(size_t)n * K + k] = f2bf_rne(f - bfhi_f32(f));
        }
    }
}

// dual-source variant: output row n<Na from Wa col n, else Wb col n-Na (heads fusion)
__global__ __launch_bounds__(256) void split_transpose2(
    const float* __restrict__ Wa, const float* __restrict__ Wb, int Na, int Nb,
    unsigned short* __restrict__ Thi, unsigned short* __restrict__ Tlo, int K)
{
    const int N = Na + Nb;
    __shared__ float tile[32][33];
    const int kt = blockIdx.x * 32, nt = blockIdx.y * 32;
    const int tx = threadIdx.x & 31, ty = threadIdx.x >> 5;
#pragma unroll
    for (int j = 0; j < 4; ++j) {
        int k = kt + ty + j * 8, n = nt + tx;
        float v = 0.f;
        if (k < K && n < N)
            v = (n < Na) ? Wa[(size_t)k * Na + n] : Wb[(size_t)k * Nb + (n - Na)];
        tile[ty + j * 8][tx] = v;
    }
    __syncthreads();
#pragma unroll
    for (int j = 0; j < 4; ++j) {
        int n = nt + ty + j * 8, k = kt + tx;
        if (n < N && k < K) {
            float f = tile[tx][ty + j * 8];
            Thi[(size_t)n * K + k] = f2bf_trunc(f);
            Tlo[(size_t)n * K + k] = f2bf_rne(f - bfhi_f32(f));
        }
    }
}

// ---------------- combined-phase bf16x3 MFMA GEMM ----------------
// C = Ahi*Bhi + Alo*Bhi + Ahi*Blo, per k-tile: stage once, 48 MFMAs per barrier pair.
// A fp32 [M][K] split on the fly; B pre-split bf16 [N][K] hi/lo. 128x128 tile.
__global__ __launch_bounds__(256) void gemm_bf16x3(
    const float* __restrict__ A, const unsigned short* __restrict__ Bhi,
    const unsigned short* __restrict__ Blo, float* __restrict__ C,
    int M, int N, int K, int klen)      // klen = K/z, multiple of 32
{
    __shared__ unsigned short Ah[4096], Al[4096], Bh[4096], Bl[4096];  // 8 KB each
    const int tid = threadIdx.x;
    const int wv = tid >> 6, ln = tid & 63;
    const int q = ln >> 4, lm = ln & 15;
    const int m0 = blockIdx.y * 128, n0 = blockIdx.x * 128;
    const int k0 = blockIdx.z * klen, k1 = k0 + klen;
    const int arow_t = (wv >> 1) * 64, bcol_t = (wv & 1) * 64;

    f32x4 acc[4][4];
#pragma unroll
    for (int i = 0; i < 4; ++i)
#pragma unroll
        for (int j = 0; j < 4; ++j) acc[i][j] = (f32x4)0.f;

    // A staging role: thread t = row r=t>>1, k-half h=t&1 (16 fp32 per iter)
    const int r = tid >> 1, h = tid & 1;
    const bool arow_ok = (m0 + r) < M;
    const float* Arow = A + (size_t)(m0 + r) * K + h * 16;

    for (int kt = k0; kt < k1; kt += 32) {
        // ---- B tiles (hi & lo): 512 chunks each via global_load_lds 16B
#pragma unroll
        for (int i = 0; i < 2; ++i) {
            int c = i * 256 + wv * 64 + ln;
            int kq = c >> 7;
            int gn = n0 + (c & 127); if (gn >= N) gn = N - 1;   // clamp (dup read, unstored)
            async_load16(Bhi + (size_t)gn * K + kt + kq * 8, &Bh[(size_t)(i * 256 + wv * 64) * 8]);
            async_load16(Blo + (size_t)gn * K + kt + kq * 8, &Bl[(size_t)(i * 256 + wv * 64) * 8]);
        }
        // ---- A tile: fp32 load, split hi/lo, write both LDS tiles
        float f[16];
        if (arow_ok) {
            const float4* ap = reinterpret_cast<const float4*>(Arow + kt);
#pragma unroll
            for (int e = 0; e < 4; ++e) {
                float4 v = ap[e];
                f[e * 4 + 0] = v.x; f[e * 4 + 1] = v.y; f[e * 4 + 2] = v.z; f[e * 4 + 3] = v.w;
            }
        } else {
#pragma unroll
            for (int e = 0; e < 16; ++e) f[e] = 0.f;
        }
        bf16x8 h0, h1, l0, l1;
#pragma unroll
        for (int e = 0; e < 8; ++e) {
            h0[e] = (short)f2bf_trunc(f[e]);
            h1[e] = (short)f2bf_trunc(f[e + 8]);
            l0[e] = (short)f2bf_rne(f[e] - bfhi_f32(f[e]));
            l1[e] = (short)f2bf_rne(f[e + 8] - bfhi_f32(f[e + 8]));
        }
        *(bf16x8*)&Ah[(size_t)((h * 2 + 0) * 128 + r) * 8] = h0;
        *(bf16x8*)&Ah[(size_t)((h * 2 + 1) * 128 + r) * 8] = h1;
        *(bf16x8*)&Al[(size_t)((h * 2 + 0) * 128 + r) * 8] = l0;
        *(bf16x8*)&Al[(size_t)((h * 2 + 1) * 128 + r) * 8] = l1;
        __syncthreads();

        // ---- fragments: chunk (q*128 + row) holds k-octet q of that row
        bf16x8 afh[4], afl[4], bfh[4], bfl[4];
#pragma unroll
        for (int mi = 0; mi < 4; ++mi) {
            int c = q * 128 + arow_t + mi * 16 + lm;
            afh[mi] = *(const bf16x8*)&Ah[(size_t)c * 8];
            afl[mi] = *(const bf16x8*)&Al[(size_t)c * 8];
        }
#pragma unroll
        for (int ni = 0; ni < 4; ++ni) {
            int c = q * 128 + bcol_t + ni * 16 + lm;
            bfh[ni] = *(const bf16x8*)&Bh[(size_t)c * 8];
            bfl[ni] = *(const bf16x8*)&Bl[(size_t)c * 8];
        }
#pragma unroll
        for (int mi = 0; mi < 4; ++mi)
#pragma unroll
            for (int ni = 0; ni < 4; ++ni) {
                acc[mi][ni] = __builtin_amdgcn_mfma_f32_16x16x32_bf16(afh[mi], bfh[ni], acc[mi][ni], 0, 0, 0);
                acc[mi][ni] = __builtin_amdgcn_mfma_f32_16x16x32_bf16(afl[mi], bfh[ni], acc[mi][ni], 0, 0, 0);
                acc[mi][ni] = __builtin_amdgcn_mfma_f32_16x16x32_bf16(afh[mi], bfl[ni], acc[mi][ni], 0, 0, 0);
            }
        __syncthreads();
    }

    // ---- store partials: C/D layout row=q*4+ri, col=lm
    float* Cz = C + (size_t)blockIdx.z * (size_t)M * (size_t)N;
#pragma unroll
    for (int mi = 0; mi < 4; ++mi)
#pragma unroll
        for (int ni = 0; ni < 4; ++ni)
#pragma unroll
            for (int ri = 0; ri < 4; ++ri) {
                int rr = m0 + arow_t + mi * 16 + q * 4 + ri;
                int cc = n0 + bcol_t + ni * 16 + lm;
                if (rr < M && cc < N) Cz[(size_t)rr * N + cc] = acc[mi][ni][ri];
            }
}

// ---------------- fp32 vector GEMM (fallback path only) ----------------
__global__ __launch_bounds__(256) void gemm_f32(
    const float* __restrict__ A, const float* __restrict__ B,
    const float* __restrict__ bias, float* __restrict__ C,
    int M, int N, int K, int ksplit, int relu)
{
    __shared__ float As[TKK][TM + 4];
    __shared__ float Bs[TKK][TN + 4];
    const int tid = threadIdx.x;
    const int tx = tid & 15, ty = tid >> 4;
    const int m0 = blockIdx.y * TM, n0 = blockIdx.x * TN;
    const int z = blockIdx.z;
    const int kstart = z * ksplit;
    const int kend = (kstart + ksplit < K) ? (kstart + ksplit) : K;
    float* Cz = C + (size_t)z * (size_t)M * (size_t)N;
    const bool nvec = ((N & 3) == 0);

    float acc[8][8];
#pragma unroll
    for (int i = 0; i < 8; ++i)
#pragma unroll
        for (int j = 0; j < 8; ++j) acc[i][j] = 0.f;

    for (int kt = kstart; kt < kend; kt += TKK) {
#pragma unroll
        for (int l = 0; l < 2; ++l) {
            int idx = tid + l * 256;
            int rr = idx >> 2, kq = idx & 3;
            float4 v = make_float4(0.f, 0.f, 0.f, 0.f);
            int gr = m0 + rr;
            if (gr < M)
                v = *reinterpret_cast<const float4*>(A + (size_t)gr * K + kt + (kq << 2));
            As[(kq << 2) + 0][rr] = v.x;
            As[(kq << 2) + 1][rr] = v.y;
            As[(kq << 2) + 2][rr] = v.z;
            As[(kq << 2) + 3][rr] = v.w;
        }
#pragma unroll
        for (int l = 0; l < 2; ++l) {
            int idx = tid + l * 256;
            int kk = idx >> 5, nq = idx & 31;
            int gn = n0 + (nq << 2);
            const float* bp = B + (size_t)(kt + kk) * N + gn;
            float4 v;
            if (nvec && gn + 3 < N) {
                v = *reinterpret_cast<const float4*>(bp);
            } else {
                v.x = (gn + 0 < N) ? bp[0] : 0.f;
                v.y = (gn + 1 < N) ? bp[1] : 0.f;
                v.z = (gn + 2 < N) ? bp[2] : 0.f;
                v.w = (gn + 3 < N) ? bp[3] : 0.f;
            }
            *reinterpret_cast<float4*>(&Bs[kk][nq << 2]) = v;
        }
        __syncthreads();
#pragma unroll
        for (int kk = 0; kk < TKK; ++kk) {
            float a[8], b[8];
            *reinterpret_cast<float4*>(&a[0]) = *reinterpret_cast<const float4*>(&As[kk][ty * 8]);
            *reinterpret_cast<float4*>(&a[4]) = *reinterpret_cast<const float4*>(&As[kk][ty * 8 + 4]);
            *reinterpret_cast<float4*>(&b[0]) = *reinterpret_cast<const float4*>(&Bs[kk][tx * 4]);
            *reinterpret_cast<float4*>(&b[4]) = *reinterpret_cast<const float4*>(&Bs[kk][64 + tx * 4]);
#pragma unroll
            for (int i = 0; i < 8; ++i)
#pragma unroll
                for (int j = 0; j < 8; ++j)
                    acc[i][j] = fmaf(a[i], b[j], acc[i][j]);
        }
        __syncthreads();
    }
#pragma unroll
    for (int i = 0; i < 8; ++i) {
        int gr = m0 + ty * 8 + i;
        if (gr >= M) continue;
#pragma unroll
        for (int j = 0; j < 8; ++j) {
            int gc = n0 + ((j < 4) ? (tx * 4 + j) : (64 + tx * 4 + (j - 4)));
            if (gc >= N) continue;
            float v = acc[i][j];
            if (bias) v += bias[gc];
            if (relu) v = fmaxf(v, 0.f);
            Cz[(size_t)gr * N + gc] = v;
        }
    }
}

// ---------------- combine split-K partials + bias (+relu) ----------------
__global__ void combine_bias_act(const float* __restrict__ P, const float* __restrict__ bias,
                                 float* __restrict__ H, int total, int N, int nsplit,
                                 int pstride, int relu)
{
    int i = blockIdx.x * blockDim.x + threadIdx.x;
    if (i >= total) return;
    float s = P[i];
    for (int j = 1; j < nsplit; ++j) s += P[i + (size_t)j * (size_t)pstride];
    s += bias[i % N];
    if (relu) s = fmaxf(s, 0.f);
    H[i] = s;
}

// combine for fused heads: dual bias (bc for col<91, br after)
__global__ void combine_head(const float* __restrict__ P, const float* __restrict__ bc,
                             const float* __restrict__ br, float* __restrict__ H,
                             int total, int nsplit, int pstride)
{
    int i = blockIdx.x * blockDim.x + threadIdx.x;
    if (i >= total) return;
    float s = P[i];
    for (int j = 1; j < nsplit; ++j) s += P[i + (size_t)j * (size_t)pstride];
    int col = i % 455;
    s += (col < 91) ? bc[col] : br[col - 91];
    H[i] = s;
}

__device__ __forceinline__ float scalar_dim(const int* p)
{
    int iv = *p;
    return (iv > 0 && iv < (1 << 20)) ? (float)iv : *reinterpret_cast<const float*>(p);
}

// ---------------- decode + softmax + threshold + per-class bucket compact ----------------
__global__ __launch_bounds__(128) void decode_compact(
    const float* __restrict__ logits, int lstr, const float* __restrict__ breg, int bstr,
    const float4* __restrict__ proposals, const int* __restrict__ ihp,
    const int* __restrict__ iwp,
    float4* __restrict__ cbox, float* __restrict__ cscore, int* __restrict__ cn,
    int* __restrict__ ccnt)
{
    const int n = blockIdx.x;
    const int c = threadIdx.x;
    __shared__ float sl[91];
    __shared__ float s_max, s_sum;
    if (c < 91) sl[c] = logits[(size_t)n * lstr + c];
    __syncthreads();
    if (c == 0) {
        float m = sl[0];
        for (int i = 1; i < 91; ++i) m = fmaxf(m, sl[i]);
        float s = 0.f;
        for (int i = 0; i < 91; ++i) s += expf(sl[i] - m);
        s_max = m; s_sum = s;
    }
    __syncthreads();
    if (c < 1 || c >= 91) return;

    const float score = expf(sl[c] - s_max) / s_sum;
    const float Wim = scalar_dim(iwp), Him = scalar_dim(ihp);
    float4 p = proposals[n];
    float pw = p.z - p.x, ph = p.w - p.y;
    float pcx = p.x + 0.5f * pw, pcy = p.y + 0.5f * ph;
    const float* r4 = breg + (size_t)n * bstr + c * 4;
    float dxv = r4[0] / 10.f, dyv = r4[1] / 10.f;
    const float BCLIP = 4.135166556742356f;
    float dwv = fminf(r4[2] / 5.f, BCLIP);
    float dhv = fminf(r4[3] / 5.f, BCLIP);
    float cx = dxv * pw + pcx, cy = dyv * ph + pcy;
    float w = expf(dwv) * pw, hh = expf(dhv) * ph;
    float x1 = cx - 0.5f * w, y1 = cy - 0.5f * hh;
    float x2 = cx + 0.5f * w, y2 = cy + 0.5f * hh;
    x1 = fminf(fmaxf(x1, 0.f), Wim);
    y1 = fminf(fmaxf(y1, 0.f), Him);
    x2 = fminf(fmaxf(x2, 0.f), Wim);
    y2 = fminf(fmaxf(y2, 0.f), Him);
    float bw = x2 - x1, bh = y2 - y1;
    if (score > 0.05f && bw >= 0.01f && bh >= 0.01f) {
        int cls = c - 1;
        int pos = atomicAdd(&ccnt[cls], 1);
        if (pos < CPC) {
            cbox[cls * CPC + pos] = make_float4(x1, y1, x2, y2);
            cscore[cls * CPC + pos] = score;
            cn[cls * CPC + pos] = n;
        }
    }
}

// ---------------- per-class greedy NMS ----------------
__global__ __launch_bounds__(256) void nms_class(
    const float4* __restrict__ cbox, const float* __restrict__ cscore,
    const int* __restrict__ cn, const int* __restrict__ ccnt,
    float4* __restrict__ sbox, float* __restrict__ sscore,
    unsigned long long* __restrict__ skey, int* __restrict__ scnt)
{
    const int cls = blockIdx.x;
    const int tid = threadIdx.x;
    int cnt = ccnt[cls]; if (cnt > CPC) cnt = CPC;

    __shared__ float4 cb[CPC];
    __shared__ unsigned long long keys[CPC];
    __shared__ unsigned long long red[4];
    __shared__ float4 selsh;
    __shared__ int selidx_sh;

    for (int i = tid; i < cnt; i += 256) {
        cb[i] = cbox[cls * CPC + i];
        unsigned int sb = __float_as_uint(cscore[cls * CPC + i]);
        sb ^= (sb >> 31) ? 0xFFFFFFFFu : 0x80000000u;
        unsigned int flat = (unsigned)cn[cls * CPC + i] * 90u + (unsigned)cls;
        keys[i] = ((unsigned long long)sb << 32) | (unsigned long long)(0xFFFFFFFFu - flat);
    }
    __syncthreads();

    int sel = 0;
    while (sel < SPC) {
        unsigned long long best = 0ull;
        for (int i = tid; i < cnt; i += 256) {
            unsigned long long k = keys[i];
            if (k > best) best = k;
        }
#pragma unroll
        for (int d = 32; d >= 1; d >>= 1) {
            unsigned long long o = __shfl_down(best, d, 64);
            if (o > best) best = o;
        }
        if ((tid & 63) == 0) red[tid >> 6] = best;
        __syncthreads();
        unsigned long long gbest = red[0];
        if (red[1] > gbest) gbest = red[1];
        if (red[2] > gbest) gbest = red[2];
        if (red[3] > gbest) gbest = red[3];
        if (gbest == 0ull) break;
        for (int i = tid; i < cnt; i += 256)
            if (keys[i] == gbest) { selsh = cb[i]; selidx_sh = i; }
        __syncthreads();
        float4 s = selsh;
        const int si = selidx_sh;
        const float sa = (s.z - s.x) * (s.w - s.y);
        if (tid == 0) {
            sbox[cls * SPC + sel] = s;
            unsigned int sb = (unsigned int)(gbest >> 32);
            sb ^= (sb >> 31) ? 0x80000000u : 0xFFFFFFFFu;
            sscore[cls * SPC + sel] = __uint_as_float(sb);
            skey[cls * SPC + sel] = gbest;
        }
        for (int i = tid; i < cnt; i += 256) {
            float4 b = cb[i];
            float xx1 = fmaxf(s.x, b.x), yy1 = fmaxf(s.y, b.y);
            float xx2 = fminf(s.z, b.z), yy2 = fminf(s.w, b.w);
            float inter = fmaxf(xx2 - xx1, 0.f) * fmaxf(yy2 - yy1, 0.f);
            float area = (b.z - b.x) * (b.w - b.y);
            if (3.f * inter > sa + area + 1e-9f || i == si) keys[i] = 0ull;
        }
        ++sel;
        __syncthreads();
    }
    if (tid == 0) scnt[cls] = sel;
}

// ---------------- 90-way merge ----------------
__global__ __launch_bounds__(128) void nms_merge(
    const float4* __restrict__ sbox, const float* __restrict__ sscore,
    const unsigned long long* __restrict__ skey, const int* __restrict__ scnt,
    float* __restrict__ out)
{
    const int tid = threadIdx.x;
    __shared__ int head[NCLS];
    __shared__ unsigned long long red[2];
    __shared__ int selc_sh;
    if (tid < NCLS) head[tid] = 0;
    __syncthreads();

    for (int k = 0; k < 100; ++k) {
        unsigned long long key = 0ull;
        if (tid < NCLS && head[tid] < scnt[tid]) key = skey[tid * SPC + head[tid]];
        unsigned long long mykey = key;
#pragma unroll
        for (int d = 32; d >= 1; d >>= 1) {
            unsigned long long o = __shfl_down(key, d, 64);
            if (o > key) key = o;
        }
        if ((tid & 63) == 0) red[tid >> 6] = key;
        if (tid == 0) selc_sh = -1;
        __syncthreads();
        unsigned long long gbest = red[0] > red[1] ? red[0] : red[1];
        if (gbest != 0ull && mykey == gbest) selc_sh = tid;
        __syncthreads();
        const int c = selc_sh;
        if (tid == 0) {
            if (c >= 0) {
                int h = head[c];
                float4 b = sbox[c * SPC + h];
                out[k * 4 + 0] = b.x; out[k * 4 + 1] = b.y;
                out[k * 4 + 2] = b.z; out[k * 4 + 3] = b.w;
                out[400 + k] = sscore[c * SPC + h];
                out[500 + k] = (float)(c + 1);
            } else {
                out[k * 4 + 0] = 0.f; out[k * 4 + 1] = 0.f;
                out[k * 4 + 2] = 0.f; out[k * 4 + 3] = 0.f;
                out[400 + k] = 0.f; out[500 + k] = 0.f;
            }
        }
        if (c >= 0 && tid == c) head[c]++;
        __syncthreads();
    }
}

// ------------------------------------------------------------------------
extern "C" void kernel_launch(void* const* d_in, const int* in_sizes, int n_in,
                              void* d_out, int out_size, void* d_ws, size_t ws_size,
                              hipStream_t stream)
{
    const float* bf    = (const float*)d_in[0];
    const float* props = (const float*)d_in[1];
    const float* W1    = (const float*)d_in[2];
    const float* b1    = (const float*)d_in[3];
    const float* W2    = (const float*)d_in[4];
    const float* b2    = (const float*)d_in[5];
    const float* Wc    = (const float*)d_in[6];
    const float* bc    = (const float*)d_in[7];
    const float* Wr    = (const float*)d_in[8];
    const float* br    = (const float*)d_in[9];
    const int*   ihp   = (const int*)d_in[10];
    const int*   iwp   = (const int*)d_in[11];
    float* ws  = (float*)d_ws;
    float* out = (float*)d_out;

    const size_t MN   = 2000ull * 1024ull;      // 2,048,000
    const size_t NLOG = 2000ull * 91ull;
    const size_t NREG = 2000ull * 364ull;
    const size_t NHEAD = 2000ull * 455ull;      // 910,000
    const size_t ws_floats = ws_size / 4;

    // ---- MFMA-path layout (float units) ----
    const size_t BT1F = 1024ull * 12544ull / 2;   // 6,422,528 per bf16 array
    const size_t WT2F = 1024ull * 1024ull / 2;    // 524,288
    const size_t WHF  = 455ull * 1024ull / 2;     // 232,960
    const size_t NMSF = (size_t)NCLS * CPC * 6 + (size_t)NCLS * SPC * 7 + 256;
    const size_t PF   = 4 * MN;                   // 8,192,000 (covers 8*NHEAD too)
    const size_t NEED = 2 * BT1F + 2 * WT2F + 2 * WHF + 2 * MN + NHEAD + NMSF + PF + 64;

    if (ws_floats >= NEED) {
        // ================= combined-phase bf16x3 MFMA path =================
        unsigned short* BT1hi = (unsigned short*)ws;
        unsigned short* BT1lo = (unsigned short*)(ws + BT1F);
        unsigned short* WT2hi = (unsigned short*)(ws + 2 * BT1F);
        unsigned short* WT2lo = (unsigned short*)(ws + 2 * BT1F + WT2F);
        unsigned short* WHhi  = (unsigned short*)(ws + 2 * BT1F + 2 * WT2F);
        unsigned short* WHlo  = (unsigned short*)(ws + 2 * BT1F + 2 * WT2F + WHF);
        float* H1   = ws + 2 * BT1F + 2 * WT2F + 2 * WHF;
        float* H2   = H1 + MN;
        float* HEAD = H2 + MN;
        float* CBOX   = HEAD + NHEAD;
        float* CSCORE = CBOX + (size_t)NCLS * CPC * 4;
        int*   CN     = (int*)(CSCORE + (size_t)NCLS * CPC);
        float* SBOX   = (float*)(CN + (size_t)NCLS * CPC);
        float* SSCORE = SBOX + (size_t)NCLS * SPC * 4;
        unsigned long long* SKEY = (unsigned long long*)(SSCORE + (size_t)NCLS * SPC);
        int*   CCNT = (int*)(SKEY + (size_t)NCLS * SPC);
        int*   SCNT = CCNT + NCLS;
        float* P = (float*)(SCNT + NCLS + 62);

        // 0) weight splits
        split_transpose<<<dim3(392, 32), 256, 0, stream>>>(W1, BT1hi, BT1lo, 12544, 1024);
        split_transpose<<<dim3(32, 32), 256, 0, stream>>>(W2, WT2hi, WT2lo, 1024, 1024);
        split_transpose2<<<dim3(32, 15), 256, 0, stream>>>(Wc, Wr, 91, 364, WHhi, WHlo, 1024);
        // 1) GEMM1: 2000x12544x1024, z=4
        gemm_bf16x3<<<dim3(8, 16, 4), 256, 0, stream>>>(bf, BT1hi, BT1lo, P,
                                                        2000, 1024, 12544, 3136);
        combine_bias_act<<<(int)((MN + 255) / 256), 256, 0, stream>>>(P, b1, H1,
                                                        (int)MN, 1024, 4, (int)MN, 1);
        // 2) GEMM2: 2000x1024x1024, z=4
        gemm_bf16x3<<<dim3(8, 16, 4), 256, 0, stream>>>(H1, WT2hi, WT2lo, P,
                                                        2000, 1024, 1024, 256);
        combine_bias_act<<<(int)((MN + 255) / 256), 256, 0, stream>>>(P, b2, H2,
                                                        (int)MN, 1024, 4, (int)MN, 1);
        // 3) fused heads: 2000x1024x455, z=8
        gemm_bf16x3<<<dim3(4, 16, 8), 256, 0, stream>>>(H2, WHhi, WHlo, P,
                                                        2000, 455, 1024, 128);
        combine_head<<<(int)((NHEAD + 255) / 256), 256, 0, stream>>>(P, bc, br, HEAD,
                                                        (int)NHEAD, 8, (int)NHEAD);
        // 4) decode + compaction; 5) per-class NMS; 6) merge
        hipMemsetAsync(CCNT, 0, 2 * NCLS * sizeof(int), stream);
        decode_compact<<<2000, 128, 0, stream>>>(HEAD, 455, HEAD + 91, 455,
                                                 (const float4*)props, ihp, iwp,
                                                 (float4*)CBOX, CSCORE, CN, CCNT);
        nms_class<<<NCLS, 256, 0, stream>>>((const float4*)CBOX, CSCORE, CN, CCNT,
                                            (float4*)SBOX, SSCORE, SKEY, SCNT);
        nms_merge<<<1, 128, 0, stream>>>((const float4*)SBOX, SSCORE, SKEY, SCNT, out);
        return;
    }

    // ================= fallback: fp32 vector path =================
    const size_t NMSF2 = (size_t)NCLS * CPC * 6 + (size_t)NCLS * SPC * 7 + 256;
    const size_t TAILF = 2 * MN + NLOG + NREG + NMSF2;
    int z1 = 2;
    if (ws_floats >= TAILF + 8 * MN) z1 = 8;
    else if (ws_floats >= TAILF + 4 * MN) z1 = 4;
    const size_t REUSE = (size_t)z1 * MN;
    int zh = (REUSE >= 8 * NREG) ? 8 : 4;

    float* P      = ws;
    float* H1     = P + REUSE;
    float* H2     = H1 + MN;
    float* LOG    = H2 + MN;
    float* BREG   = LOG + NLOG;
    float* CBOX   = BREG + NREG;
    float* CSCORE = CBOX + (size_t)NCLS * CPC * 4;
    int*   CN     = (int*)(CSCORE + (size_t)NCLS * CPC);
    float* SBOX   = (float*)(CN + (size_t)NCLS * CPC);
    float* SSCORE = SBOX + (size_t)NCLS * SPC * 4;
    unsigned long long* SKEY = (unsigned long long*)(SSCORE + (size_t)NCLS * SPC);
    int*   CCNT   = (int*)(SKEY + (size_t)NCLS * SPC);
    int*   SCNT   = CCNT + NCLS;

    gemm_f32<<<dim3(8, 16, z1), 256, 0, stream>>>(bf, W1, nullptr, P,
                                                  2000, 1024, 12544, 12544 / z1, 0);
    combine_bias_act<<<(int)((MN + 255) / 256), 256, 0, stream>>>(P, b1, H1,
                                                  (int)MN, 1024, z1, (int)MN, 1);
    gemm_f32<<<dim3(8, 16, 4), 256, 0, stream>>>(H1, W2, nullptr, P,
                                                 2000, 1024, 1024, 256, 0);
    combine_bias_act<<<(int)((MN + 255) / 256), 256, 0, stream>>>(P, b2, H2,
                                                 (int)MN, 1024, 4, (int)MN, 1);
    gemm_f32<<<dim3(1, 16, zh), 256, 0, stream>>>(H2, Wc, nullptr, P,
                                                  2000, 91, 1024, 1024 / zh, 0);
    combine_bias_act<<<(int)((NLOG + 255) / 256), 256, 0, stream>>>(P, bc, LOG,
                                                  (int)NLOG, 91, zh, (int)NLOG, 0);
    gemm_f32<<<dim3(3, 16, zh), 256, 0, stream>>>(H2, Wr, nullptr, P,
                                                  2000, 364, 1024, 1024 / zh, 0);
    combine_bias_act<<<(int)((NREG + 255) / 256), 256, 0, stream>>>(P, br, BREG,
                                                  (int)NREG, 364, zh, (int)NREG, 0);
    hipMemsetAsync(CCNT, 0, 2 * NCLS * sizeof(int), stream);
    decode_compact<<<2000, 128, 0, stream>>>(LOG, 91, BREG, 364,
                                             (const float4*)props, ihp, iwp,
                                             (float4*)CBOX, CSCORE, CN, CCNT);
    nms_class<<<NCLS, 256, 0, stream>>>((const float4*)CBOX, CSCORE, CN, CCNT,
                                        (float4*)SBOX, SSCORE, SKEY, SCNT);
    nms_merge<<<1, 128, 0, stream>>>((const float4*)SBOX, SSCORE, SKEY, SCNT, out);
}